// Round 6
// baseline (290.488 us; speedup 1.0000x reference)
//
#include <hip/hip_runtime.h>

// Problem constants (fixed by setup_inputs) — ALL TENSORS ARE FLOAT32.
#define B 4
#define H 16
#define S 2048
#define D 64
#define M 1000
#define TOPKN 10
#define HID 1024   // H*D

// Flat output element offsets (f32 elements)
//  out0 inputs  [4,2048,1024]   @ 0
//  out1 q       [4,16,2048,64]  @ 8388608
//  out2 k_aug   [4,16,2058,64]  @ 16777216
//  out3 v_aug   [4,16,2058,64]  @ 25206784
//  out4 mask_aug[4,2058]        @ 33636352
//  out5 seq_len_k scalar        @ 33644584
//  out6 positions_k [4,2058]    @ 33644585   (total 33652817 elems)
#define O4E 33636352U
#define O5E 33644584U
#define O6E 33644585U
// float4-chunk constants (4 f32 = 16 B per chunk)
#define O2C 4194304U   // out2 offset in chunks
#define O3C 6301696U   // out3 offset in chunks
#define BHSTR 32928U   // 2058*64/4 chunks per (b,h) in k_aug/v_aug
#define CF 2097152U    // 8,388,608 elems / 4 per flat region

#define NSIMS 125     // 8 rows each = M exactly
#define NCOPY 8192    // copy blocks: 8192 * 1024 chunks = 8,388,608 exactly

__device__ __forceinline__ void chunk_src_dst(
    unsigned int c, const float4* __restrict__ s0,
    const float4* __restrict__ s1, const float4* __restrict__ s2,
    const float4* __restrict__ s3, float4& val, unsigned int& dst) {
  if (c < CF) {
    val = s0[c];
    dst = c;
  } else if (c < 2u * CF) {
    val = s1[c - CF];
    dst = c;
  } else {
    bool isv = (c >= 3u * CF);
    unsigned int idx = c - (isv ? 3u : 2u) * CF;
    unsigned int bh = idx >> 15;  // 2048*64/4 = 32768 chunks per (b,h)
    unsigned int r = idx & 32767u;
    dst = (isv ? O3C : O2C) + bh * BHSTR + 160u + r;  // skip 10 retrieved rows
    val = (isv ? s3 : s2)[idx];
  }
}

// ---------------------------------------------------------------------------
// Copy kernel: blit-mimic. No LDS, minimal VGPR, huge grid, one float4
// load -> store per step, lanes perfectly coalesced (1 KB/instruction).
// Separate dispatch so rocprof isolates its duration + BW.
__global__ __launch_bounds__(256) void copy_kernel(
    const float* __restrict__ in0, const float* __restrict__ qin,
    const float* __restrict__ kin, const float* __restrict__ vin,
    float* __restrict__ out, unsigned int outElems) {
  const unsigned int outChunks = outElems >> 2;
  const float4* s0 = (const float4*)in0;
  const float4* s1 = (const float4*)qin;
  const float4* s2 = (const float4*)kin;
  const float4* s3 = (const float4*)vin;
  float4* o = (float4*)out;
  unsigned int base = blockIdx.x * 1024u + threadIdx.x;
#pragma unroll
  for (int k = 0; k < 4; ++k) {
    unsigned int c = base + (unsigned int)k * 256u;
    float4 v;
    unsigned int d;
    chunk_src_dst(c, s0, s1, s2, s3, v, d);
    if (d < outChunks) o[d] = v;
  }
}

// ---------------------------------------------------------------------------
// Sims kernel: sims[b][m] = cos-sim(query_key[b], mem_keys[m]) -> ws.
// One wave per 2 rows, coalesced row reads, shuffle reduce.
__global__ __launch_bounds__(256) void sims_kernel(
    const float* __restrict__ kin, const float* __restrict__ mkeys,
    float* __restrict__ ws) {
  const int blk = blockIdx.x;
  const int tid = threadIdx.x;

  __shared__ float4 s_q4[B][256];  // 4 query vectors, float4-packed (16 KB)
  __shared__ float s_qn[B];

  // Load all 4 query vectors: query_key[b][h*64+d] = k[b, h, S-1, d].
  for (int i = tid; i < B * 256; i += 256) {
    int b = i >> 8, c = i & 255;
    int h = c >> 4, dd = (c & 15) << 2;
    s_q4[b][c] = *(const float4*)(kin +
                                  ((size_t)(b * H + h) * S + (S - 1)) * D +
                                  dd);
  }
  __syncthreads();

  const int lane = tid & 63;
  const int w = tid >> 6;  // wave id 0..3

  // q norms: wave w reduces batch w
  {
    float ss = 0.f;
    for (int j = 0; j < 4; ++j) {
      float4 v = s_q4[w][lane + j * 64];
      ss += v.x * v.x + v.y * v.y + v.z * v.z + v.w * v.w;
    }
    for (int off = 32; off; off >>= 1) ss += __shfl_xor(ss, off);
    if (lane == 0) s_qn[w] = sqrtf(ss) + 1e-8f;
  }
  __syncthreads();

  // Each wave: 2 rows; lanes read the 4 KB row coalesced (64x16B chunks).
  const float4* mk4 = (const float4*)mkeys;
  for (int r = 0; r < 2; ++r) {
    const int m = blk * 8 + w * 2 + r;  // always < M (125*8 = 1000)
    float d0 = 0.f, d1 = 0.f, d2 = 0.f, d3 = 0.f, msq = 0.f;
#pragma unroll
    for (int j = 0; j < 4; ++j) {
      float4 ch = mk4[(size_t)m * 256 + lane + j * 64];
      float4 q0 = s_q4[0][lane + j * 64];
      float4 q1 = s_q4[1][lane + j * 64];
      float4 q2 = s_q4[2][lane + j * 64];
      float4 q3 = s_q4[3][lane + j * 64];
      d0 += q0.x * ch.x + q0.y * ch.y + q0.z * ch.z + q0.w * ch.w;
      d1 += q1.x * ch.x + q1.y * ch.y + q1.z * ch.z + q1.w * ch.w;
      d2 += q2.x * ch.x + q2.y * ch.y + q2.z * ch.z + q2.w * ch.w;
      d3 += q3.x * ch.x + q3.y * ch.y + q3.z * ch.z + q3.w * ch.w;
      msq += ch.x * ch.x + ch.y * ch.y + ch.z * ch.z + ch.w * ch.w;
    }
    for (int off = 32; off; off >>= 1) {
      d0 += __shfl_xor(d0, off);
      d1 += __shfl_xor(d1, off);
      d2 += __shfl_xor(d2, off);
      d3 += __shfl_xor(d3, off);
      msq += __shfl_xor(msq, off);
    }
    if (lane == 0) {
      float den = sqrtf(msq) + 1e-8f;  // same formula as proven kernel
      ws[0 * 1024 + m] = d0 / (s_qn[0] * den);
      ws[1 * 1024 + m] = d1 / (s_qn[1] * den);
      ws[2 * 1024 + m] = d2 / (s_qn[2] * den);
      ws[3 * 1024 + m] = d3 / (s_qn[3] * den);
    }
  }
}

// ---------------------------------------------------------------------------
// Stage 2: per-batch top-10 from ws + mask/positions/seq_len + gather.
__global__ __launch_bounds__(256) void fused_stage2(
    const float* __restrict__ amask, const float* __restrict__ mkeys,
    const float* __restrict__ mvals, const float* __restrict__ mpos,
    const float* __restrict__ ws, float* __restrict__ out,
    unsigned int outElems) {
  const int b = blockIdx.x;
  const int tid = threadIdx.x;
  const unsigned int outChunks = outElems >> 2;
  const int SK = S + TOPKN;  // 2058

  __shared__ float s_sims[1024];  // sims padded with -inf
  __shared__ float s_rv[256];
  __shared__ int s_ri[256];
  __shared__ int s_top[TOPKN];

  for (int i = tid; i < 1024; i += 256)
    s_sims[i] = (i < M) ? ws[b * 1024 + i] : -INFINITY;

  // mask_aug = [ones(K), mask]; positions_k[0:S] = arange(S)
  for (int i = tid; i < SK; i += 256) {
    unsigned int d4 = O4E + (unsigned int)(b * SK + i);
    if (d4 < outElems)
      out[d4] = (i < TOPKN) ? 1.0f : amask[b * S + (i - TOPKN)];
    unsigned int d6 = O6E + (unsigned int)(b * SK + i);
    if (i < S && d6 < outElems) out[d6] = (float)i;
  }
  if (b == 0 && tid == 0 && O5E < outElems)
    out[O5E] = 2064.0f;  // ref value is bf16-rounded 2058 (proven round 0)
  __syncthreads();

  // top-10: LDS-tree argmax x10 (ties -> lowest index, JAX semantics).
  // bi always a valid in-range index — NaN-proof, no sentinel can escape.
  for (int t = 0; t < TOPKN; ++t) {
    int base = tid * 4;
    float bv = s_sims[base];
    int bi = base;
    for (int j = 1; j < 4; ++j) {
      float v = s_sims[base + j];
      if (v > bv) { bv = v; bi = base + j; }  // '>' keeps lowest index
    }
    s_rv[tid] = bv;
    s_ri[tid] = bi;
    __syncthreads();
    for (int w = 128; w > 0; w >>= 1) {
      if (tid < w) {
        float ov = s_rv[tid + w];
        int oi = s_ri[tid + w];
        if (ov > s_rv[tid] || (ov == s_rv[tid] && oi < s_ri[tid])) {
          s_rv[tid] = ov;
          s_ri[tid] = oi;
        }
      }
      __syncthreads();
    }
    if (tid == 0) {
      int sel = s_ri[0];                     // in [0,1024) by construction
      s_sims[sel] = -INFINITY;
      s_top[t] = (sel < M) ? sel : (M - 1);  // clamp for gather safety
    }
    __syncthreads();
  }

  // r_pos tail of positions_k
  if (tid < TOPKN) {
    unsigned int d6 = O6E + (unsigned int)(b * SK + S + tid);
    if (d6 < outElems) out[d6] = mpos[s_top[tid]];
  }

  // gather retrieved rows: k_aug/v_aug[b,h,kk,:] = mem[im][h*64 .. h*64+63]
  // 2 * H * TOPK * 16 chunks = 5120 chunks per batch.
  const float4* mk4 = (const float4*)mkeys;
  const float4* mv4 = (const float4*)mvals;
  float4* o = (float4*)out;
  for (int c = tid; c < 5120; c += 256) {
    int isv = (c >= 2560);
    int cc = isv ? c - 2560 : c;
    int row = cc >> 4, ch = cc & 15;  // 16 chunks per 64-elem row
    int h = row / 10, kk = row - h * 10;
    int im = s_top[kk];               // clamped to [0, M)
    const float4* src = isv ? mv4 : mk4;
    unsigned int dst = (isv ? O3C : O2C) +
                       (unsigned int)((b * H + h) * BHSTR + kk * 16 + ch);
    if (dst < outChunks) o[dst] = src[(size_t)im * 256 + h * 16 + ch];
  }
}

// ---------------------------------------------------------------------------
extern "C" void kernel_launch(void* const* d_in, const int* in_sizes, int n_in,
                              void* d_out, int out_size, void* d_ws, size_t ws_size,
                              hipStream_t stream) {
  const float* in0 = (const float*)d_in[0];  // inputs  [4,2048,1024]
  const float* q   = (const float*)d_in[1];  // q       [4,16,2048,64]
  const float* k   = (const float*)d_in[2];  // k
  const float* v   = (const float*)d_in[3];  // v
  const float* am  = (const float*)d_in[4];  // attention_mask [4,2048]
  const float* mk  = (const float*)d_in[5];  // mem_keys   [1000,1024]
  const float* mv  = (const float*)d_in[6];  // mem_values [1000,1024]
  const float* mp  = (const float*)d_in[7];  // mem_positions [1000]
  // d_in[8] = seq_len_q (unused; S fixed at 2048)
  (void)in_sizes; (void)n_in; (void)ws_size;

  float* out = (float*)d_out;
  float* ws = (float*)d_ws;  // needs B*1024*4 = 16 KB; harness ws is larger

  // 1) sims (small; reads k + mem_keys only)
  sims_kernel<<<NSIMS, 256, 0, stream>>>(k, mk, ws);
  // 2) bulk copy — isolated dispatch, blit-mimic structure (no LDS,
  //    minimal VGPR, 32768 waves, 1 KB coalesced per instruction)
  copy_kernel<<<NCOPY, 256, 0, stream>>>(in0, q, k, v, out,
                                         (unsigned int)out_size);
  // 3) top-k + retrieved-row gather + mask/positions/seq_len
  fused_stage2<<<B, 256, 0, stream>>>(am, mk, mv, mp, ws, out,
                                      (unsigned int)out_size);
}